// Round 1
// baseline (630.178 us; speedup 1.0000x reference)
//
#include <hip/hip_runtime.h>
#include <cstdint>
#include <cstddef>

static constexpr float NEG_SLOPE_C = 0.2f;
static constexpr float EPS_C = 1e-16f;

// ---------------- CSR construction ----------------

__global__ void degree_kernel(const int* __restrict__ ei, const float* __restrict__ ew,
                              int E, int* __restrict__ cnt, float* __restrict__ wsum) {
    int e = blockIdx.x * blockDim.x + threadIdx.x;
    if (e >= E) return;
    int dst = ei[E + e];
    atomicAdd(&cnt[dst], 1);
    atomicAdd(&wsum[dst], ew[e]);
}

// single block, 1024 threads: exclusive scan of cnt -> offs, plus self-loop weights
__global__ void scan_kernel(const int* __restrict__ cnt, const float* __restrict__ wsum,
                            int N, int E, int* __restrict__ offs, float* __restrict__ self_w) {
    __shared__ int bufA[1024];
    __shared__ int bufB[1024];
    int t = threadIdx.x;
    int chunk = (N + 1023) / 1024;
    int lo = t * chunk;
    int hi = lo + chunk; if (hi > N) hi = N; if (lo > N) lo = N;
    int s = 0;
    for (int n = lo; n < hi; ++n) s += cnt[n];
    bufA[t] = s;
    __syncthreads();
    int* srcb = bufA; int* dstb = bufB;
    for (int d = 1; d < 1024; d <<= 1) {
        int v = srcb[t];
        if (t >= d) v += srcb[t - d];
        dstb[t] = v;
        __syncthreads();
        int* tmp = srcb; srcb = dstb; dstb = tmp;
    }
    int run = (t == 0) ? 0 : srcb[t - 1];
    for (int n = lo; n < hi; ++n) { offs[n] = run; run += cnt[n]; }
    if (t == 0) offs[N] = E;
    for (int n = t; n < N; n += 1024) {
        int c = cnt[n];
        self_w[n] = (c > 0) ? (wsum[n] / (float)c) : 0.0f;
    }
}

__global__ void scatter_kernel(const int* __restrict__ ei, const float* __restrict__ ew, int E,
                               const int* __restrict__ offs, int* __restrict__ cursor,
                               int* __restrict__ csr_src, float* __restrict__ csr_w) {
    int e = blockIdx.x * blockDim.x + threadIdx.x;
    if (e >= E) return;
    int dst = ei[E + e];
    int pos = offs[dst] + atomicAdd(&cursor[dst], 1);
    csr_src[pos] = ei[e];
    csr_w[pos] = ew[e];
}

// ---------------- fp32 GEMM: out[R x 128] = X[R x K] @ W[K x 128] ----------------
// 64 rows x 128 cols per block of 256 threads; each thread: 8 rows x 4 cols.

template<int K>
__global__ __launch_bounds__(256) void gemm_kernel(const float* __restrict__ X,
                                                   const float* __restrict__ W,
                                                   float* __restrict__ out, int R) {
    __shared__ float xs[64 * K];
    int tid = threadIdx.x;
    int rowBase = blockIdx.x * 64;
    // stage 64xK X tile (contiguous rows) via float4
    const float4* Xv = (const float4*)(X + (size_t)rowBase * K);
    float4* xsv = (float4*)xs;
    constexpr int NV = 64 * K / 4;
    #pragma unroll
    for (int i = 0; i < NV / 256; ++i) xsv[tid + i * 256] = Xv[tid + i * 256];
    __syncthreads();

    int cg = tid & 31;   // col group -> cols cg*4 .. cg*4+3
    int rg = tid >> 5;   // row group -> rows rg*8 .. rg*8+7
    float4 acc[8];
    #pragma unroll
    for (int j = 0; j < 8; ++j) acc[j] = make_float4(0.f, 0.f, 0.f, 0.f);
    const float4* Wv = (const float4*)W;   // K rows of 32 float4
    const float* xrow = xs + rg * 8 * K;
    #pragma unroll 4
    for (int k = 0; k < K; ++k) {
        float4 w = Wv[k * 32 + cg];
        #pragma unroll
        for (int j = 0; j < 8; ++j) {
            float xv = xrow[j * K + k];
            acc[j].x += xv * w.x; acc[j].y += xv * w.y;
            acc[j].z += xv * w.z; acc[j].w += xv * w.w;
        }
    }
    float4* outv = (float4*)out;
    #pragma unroll
    for (int j = 0; j < 8; ++j) {
        size_t r = (size_t)(rowBase + rg * 8 + j);
        outv[r * 32 + cg] = acc[j];
    }
}

// ---------------- fused edge softmax-aggregate (one wave per (m, node)) ----------------
// lane c handles channel c (head 0) and channel 64+c (head 1).

__global__ __launch_bounds__(256) void edge_kernel(
    const float* __restrict__ xl, const float* __restrict__ xr,
    const int* __restrict__ offs, const int* __restrict__ csr_src,
    const float* __restrict__ csr_w, const float* __restrict__ self_w,
    const float* __restrict__ att, const float* __restrict__ We,
    const float* __restrict__ bias, float* __restrict__ out,
    int N, int M) {
    int task = blockIdx.x * 4 + (threadIdx.x >> 6);
    if (task >= M * N) return;
    int lane = threadIdx.x & 63;
    int n = task / M;
    int m = task - n * M;

    size_t base_i = ((size_t)m * N + n) * 128;
    float xi0 = xr[base_i + lane];
    float xi1 = xr[base_i + 64 + lane];
    float att0 = att[lane], att1 = att[64 + lane];
    float we0 = We[lane], we1 = We[64 + lane];

    int beg = offs[n], end = offs[n + 1];
    float mr0 = -1e30f, mr1 = -1e30f;
    float l0 = 0.f, l1 = 0.f, acc0 = 0.f, acc1 = 0.f;

    for (int e = beg - 1; e < end; ++e) {
        int src; float w;
        if (e < beg) { src = n; w = self_w[n]; }          // self-loop first
        else         { src = csr_src[e]; w = csr_w[e]; }
        size_t base_j = ((size_t)m * N + src) * 128;
        float xj0 = xl[base_j + lane];
        float xj1 = xl[base_j + 64 + lane];
        float s0 = xi0 + xj0 + w * we0;
        float s1 = xi1 + xj1 + w * we1;
        s0 = fmaxf(s0, 0.f) + NEG_SLOPE_C * fminf(s0, 0.f);
        s1 = fmaxf(s1, 0.f) + NEG_SLOPE_C * fminf(s1, 0.f);
        float p0 = s0 * att0;
        float p1 = s1 * att1;
        #pragma unroll
        for (int d = 1; d < 64; d <<= 1) {
            p0 += __shfl_xor(p0, d, 64);
            p1 += __shfl_xor(p1, d, 64);
        }
        // online softmax update (wave-uniform per head -> no divergence)
        float nm0 = fmaxf(mr0, p0), nm1 = fmaxf(mr1, p1);
        float sc0 = __expf(mr0 - nm0), sc1 = __expf(mr1 - nm1);
        float t0 = __expf(p0 - nm0), t1 = __expf(p1 - nm1);
        l0 = l0 * sc0 + t0;       l1 = l1 * sc1 + t1;
        acc0 = acc0 * sc0 + t0 * xj0;
        acc1 = acc1 * sc1 + t1 * xj1;
        mr0 = nm0; mr1 = nm1;
    }

    float o0 = acc0 / (l0 + EPS_C) + bias[lane];
    float o1 = acc1 / (l1 + EPS_C) + bias[64 + lane];
    o0 = o0 > 0.f ? o0 : expm1f(o0);   // ELU
    o1 = o1 > 0.f ? o1 : expm1f(o1);
    out[base_i + lane] = o0;
    out[base_i + 64 + lane] = o1;
}

// ---------------- launch ----------------

extern "C" void kernel_launch(void* const* d_in, const int* in_sizes, int n_in,
                              void* d_out, int out_size, void* d_ws, size_t ws_size,
                              hipStream_t stream) {
    const float* x    = (const float*)d_in[0];
    const int*   ei   = (const int*)d_in[1];
    const float* ew   = (const float*)d_in[2];
    const float* Wl1  = (const float*)d_in[3];
    const float* Wr1  = (const float*)d_in[4];
    const float* att1 = (const float*)d_in[5];
    const float* We1  = (const float*)d_in[6];
    const float* b1   = (const float*)d_in[7];
    const float* Wl2  = (const float*)d_in[8];
    const float* Wr2  = (const float*)d_in[9];
    const float* att2 = (const float*)d_in[10];
    const float* We2  = (const float*)d_in[11];
    const float* b2   = (const float*)d_in[12];

    const int E = in_sizes[1] / 2;
    const int N = 5000;                 // fixed by setup_inputs
    const int R = out_size / 128;       // M*N rows
    const int M = R / N;                // B*T = 16

    char* ws = (char*)d_ws;
    size_t off = 0;
    auto alloc = [&](size_t bytes) {
        char* p = ws + off;
        off = (off + bytes + 255) & ~(size_t)255;
        return p;
    };
    int*   cnt    = (int*)  alloc((size_t)N * 4);
    float* wsum   = (float*)alloc((size_t)N * 4);
    float* selfw  = (float*)alloc((size_t)N * 4);
    int*   offs   = (int*)  alloc((size_t)(N + 1) * 4);
    int*   cursor = (int*)  alloc((size_t)N * 4);
    int*   csrc   = (int*)  alloc((size_t)E * 4);
    float* csw    = (float*)alloc((size_t)E * 4);
    float* bufA   = (float*)alloc((size_t)R * 128 * 4);
    float* bufB   = (float*)alloc((size_t)R * 128 * 4);
    float* bufC   = (float*)alloc((size_t)R * 128 * 4);

    hipMemsetAsync(cnt,    0, (size_t)N * 4, stream);
    hipMemsetAsync(wsum,   0, (size_t)N * 4, stream);
    hipMemsetAsync(cursor, 0, (size_t)N * 4, stream);

    int eb = (E + 255) / 256;
    degree_kernel<<<eb, 256, 0, stream>>>(ei, ew, E, cnt, wsum);
    scan_kernel<<<1, 1024, 0, stream>>>(cnt, wsum, N, E, offs, selfw);
    scatter_kernel<<<eb, 256, 0, stream>>>(ei, ew, E, offs, cursor, csrc, csw);

    int gb = R / 64;
    int tb = (M * N + 3) / 4;

    // layer 1: Din=64
    gemm_kernel<64><<<gb, 256, 0, stream>>>(x, Wl1, bufA, R);   // xl1
    gemm_kernel<64><<<gb, 256, 0, stream>>>(x, Wr1, bufB, R);   // xr1
    edge_kernel<<<tb, 256, 0, stream>>>(bufA, bufB, offs, csrc, csw, selfw,
                                        att1, We1, b1, bufC, N, M);
    // layer 2: Din=128
    gemm_kernel<128><<<gb, 256, 0, stream>>>(bufC, Wl2, bufA, R);  // xl2
    gemm_kernel<128><<<gb, 256, 0, stream>>>(bufC, Wr2, bufB, R);  // xr2
    edge_kernel<<<tb, 256, 0, stream>>>(bufA, bufB, offs, csrc, csw, selfw,
                                        att2, We2, b2, (float*)d_out, N, M);
}

// Round 3
// 482.358 us; speedup vs baseline: 1.3065x; 1.3065x over previous
//
#include <hip/hip_runtime.h>
#include <cstdint>
#include <cstddef>

static constexpr float NEG_SLOPE_C = 0.2f;
static constexpr float EPS_C = 1e-16f;
static constexpr float LOG2E_C = 1.4426950408889634f;

#if defined(__has_builtin)
#if __has_builtin(__builtin_amdgcn_exp2f)
#define EXP2F(x) __builtin_amdgcn_exp2f(x)
#else
#define EXP2F(x) exp2f(x)
#endif
#else
#define EXP2F(x) exp2f(x)
#endif

// ---------------- CSR construction ----------------

__global__ void degree_kernel(const int* __restrict__ ei, const float* __restrict__ ew,
                              int E, int* __restrict__ cnt, float* __restrict__ wsum) {
    int e = blockIdx.x * blockDim.x + threadIdx.x;
    if (e >= E) return;
    int dst = ei[E + e];
    atomicAdd(&cnt[dst], 1);
    atomicAdd(&wsum[dst], ew[e]);
}

// single block, 1024 threads: exclusive scan of cnt -> offs, plus self-loop weights
__global__ void scan_kernel(const int* __restrict__ cnt, const float* __restrict__ wsum,
                            int N, int E, int* __restrict__ offs, float* __restrict__ self_w) {
    __shared__ int bufA[1024];
    __shared__ int bufB[1024];
    int t = threadIdx.x;
    int chunk = (N + 1023) / 1024;
    int lo = t * chunk;
    int hi = lo + chunk; if (hi > N) hi = N; if (lo > N) lo = N;
    int s = 0;
    for (int n = lo; n < hi; ++n) s += cnt[n];
    bufA[t] = s;
    __syncthreads();
    int* srcb = bufA; int* dstb = bufB;
    for (int d = 1; d < 1024; d <<= 1) {
        int v = srcb[t];
        if (t >= d) v += srcb[t - d];
        dstb[t] = v;
        __syncthreads();
        int* tmp = srcb; srcb = dstb; dstb = tmp;
    }
    int run = (t == 0) ? 0 : srcb[t - 1];
    for (int n = lo; n < hi; ++n) { offs[n] = run; run += cnt[n]; }
    if (t == 0) offs[N] = E;
    for (int n = t; n < N; n += 1024) {
        int c = cnt[n];
        self_w[n] = (c > 0) ? (wsum[n] / (float)c) : 0.0f;
    }
}

__global__ void scatter_kernel(const int* __restrict__ ei, const float* __restrict__ ew, int E,
                               const int* __restrict__ offs, int* __restrict__ cursor,
                               int2* __restrict__ pairs) {
    int e = blockIdx.x * blockDim.x + threadIdx.x;
    if (e >= E) return;
    int dst = ei[E + e];
    int pos = offs[dst] + atomicAdd(&cursor[dst], 1);
    pairs[pos] = make_int2(ei[e], __float_as_int(ew[e]));
}

// ---------------- fused fp32 GEMM: [outL|outR] = X[R x K] @ [Wl|Wr] (each K x 128) --
// 64 rows x (128+128) cols per block of 256 threads; each thread: 8 rows x (4+4) cols.

__device__ __forceinline__ void fma4(float4& a, float s, const float4& b) {
    a.x = fmaf(s, b.x, a.x);
    a.y = fmaf(s, b.y, a.y);
    a.z = fmaf(s, b.z, a.z);
    a.w = fmaf(s, b.w, a.w);
}

template<int K>
__global__ __launch_bounds__(256) void gemm2_kernel(const float* __restrict__ X,
                                                    const float* __restrict__ Wl,
                                                    const float* __restrict__ Wr,
                                                    float* __restrict__ outL,
                                                    float* __restrict__ outR, int R) {
    __shared__ float xs[64 * K];
    const int tid = threadIdx.x;
    const int rowBase = blockIdx.x * 64;
    const float4* Xv = (const float4*)(X + (size_t)rowBase * K);
    float4* xsv = (float4*)xs;
    constexpr int NV = 16 * K;          // float4 count of the tile
    #pragma unroll
    for (int i = 0; i < NV / 256; ++i) xsv[tid + i * 256] = Xv[tid + i * 256];
    __syncthreads();

    const int cg = tid & 31;            // cols cg*4..cg*4+3 in both halves
    const int rg = tid >> 5;            // rows rg*8..rg*8+7
    float4 aL[8], aR[8];
    #pragma unroll
    for (int j = 0; j < 8; ++j) {
        aL[j] = make_float4(0.f, 0.f, 0.f, 0.f);
        aR[j] = make_float4(0.f, 0.f, 0.f, 0.f);
    }
    const float4* Wlv = (const float4*)Wl;    // K rows of 32 float4
    const float4* Wrv = (const float4*)Wr;
    const float* xbase = xs + rg * 8 * K;

    for (int k0 = 0; k0 < K; k0 += 4) {
        float4 wl0 = Wlv[(k0 + 0) * 32 + cg];
        float4 wl1 = Wlv[(k0 + 1) * 32 + cg];
        float4 wl2 = Wlv[(k0 + 2) * 32 + cg];
        float4 wl3 = Wlv[(k0 + 3) * 32 + cg];
        float4 wr0 = Wrv[(k0 + 0) * 32 + cg];
        float4 wr1 = Wrv[(k0 + 1) * 32 + cg];
        float4 wr2 = Wrv[(k0 + 2) * 32 + cg];
        float4 wr3 = Wrv[(k0 + 3) * 32 + cg];
        #pragma unroll
        for (int j = 0; j < 8; ++j) {
            float4 xv = *(const float4*)(xbase + j * K + k0);
            fma4(aL[j], xv.x, wl0); fma4(aL[j], xv.y, wl1);
            fma4(aL[j], xv.z, wl2); fma4(aL[j], xv.w, wl3);
            fma4(aR[j], xv.x, wr0); fma4(aR[j], xv.y, wr1);
            fma4(aR[j], xv.z, wr2); fma4(aR[j], xv.w, wr3);
        }
    }
    float4* oL = (float4*)outL;
    float4* oR = (float4*)outR;
    #pragma unroll
    for (int j = 0; j < 8; ++j) {
        size_t r = (size_t)(rowBase + rg * 8 + j);
        oL[r * 32 + cg] = aL[j];
        oR[r * 32 + cg] = aR[j];
    }
}

// ---------------- fused edge softmax-aggregate ----------------
// One wave per (m, node). Lane l holds channels 2l, 2l+1 (float2):
// head 0 -> lanes 0..31, head 1 -> lanes 32..63. 5-step butterfly confined
// to 32-lane halves reduces both heads at once; per-lane result IS the
// lane's head logit (no broadcast). Graph-walk scalars (n, beg, end, e,
// src, w) made compiler-uniform via readfirstlane -> s_load path.

__global__ __launch_bounds__(256) void edge_kernel(
    const float* __restrict__ xl, const float* __restrict__ xr,
    const int* __restrict__ offs, const int2* __restrict__ pairs,
    const float* __restrict__ self_w,
    const float* __restrict__ att, const float* __restrict__ We,
    const float* __restrict__ bias, float* __restrict__ out,
    int N, int M) {
    const int wave = __builtin_amdgcn_readfirstlane(threadIdx.x >> 6);
    const int task = blockIdx.x * 4 + wave;
    if (task >= M * N) return;
    const int lane = threadIdx.x & 63;
    const int n = task / M;           // uniform
    const int m = task - n * M;       // uniform

    const int c2 = lane << 1;
    float2 att2 = *(const float2*)(att + c2);
    att2.x *= LOG2E_C; att2.y *= LOG2E_C;     // fold ln2 into att -> exp2 domain
    const float2 we2 = *(const float2*)(We + c2);

    const float* xlm = xl + (size_t)m * N * 128;
    const float* xrm = xr + (size_t)m * N * 128;
    const int rowb = n << 7;
    const float2 xi2 = *(const float2*)(xrm + rowb + c2);

    float mr, lsum;
    float2 acc;
    {   // self-loop first (always present; weight 0 for isolated nodes)
        const float sw = self_w[n];
        const float2 xj = *(const float2*)(xlm + rowb + c2);
        float sx = fmaf(sw, we2.x, xi2.x) + xj.x;
        float sy = fmaf(sw, we2.y, xi2.y) + xj.y;
        sx = fmaxf(sx, 0.f) + NEG_SLOPE_C * fminf(sx, 0.f);
        sy = fmaxf(sy, 0.f) + NEG_SLOPE_C * fminf(sy, 0.f);
        float q = sx * att2.x + sy * att2.y;
        q += __shfl_xor(q, 16, 64);
        q += __shfl_xor(q, 8, 64);
        q += __shfl_xor(q, 4, 64);
        q += __shfl_xor(q, 2, 64);
        q += __shfl_xor(q, 1, 64);
        mr = q; lsum = 1.f; acc = xj;   // t = exp2(0) = 1
    }

    const int beg = offs[n], end = offs[n + 1];
    for (int e = beg; e < end; ++e) {
        const int2 pr = pairs[e];                 // uniform -> s_load path
        const int src = pr.x;
        const float w = __int_as_float(pr.y);
        const float2 xj = *(const float2*)(xlm + (src << 7) + c2);
        float sx = fmaf(w, we2.x, xi2.x) + xj.x;
        float sy = fmaf(w, we2.y, xi2.y) + xj.y;
        sx = fmaxf(sx, 0.f) + NEG_SLOPE_C * fminf(sx, 0.f);
        sy = fmaxf(sy, 0.f) + NEG_SLOPE_C * fminf(sy, 0.f);
        float q = sx * att2.x + sy * att2.y;
        q += __shfl_xor(q, 16, 64);
        q += __shfl_xor(q, 8, 64);
        q += __shfl_xor(q, 4, 64);
        q += __shfl_xor(q, 2, 64);
        q += __shfl_xor(q, 1, 64);
        // q is now this lane's head logit (exp2 domain). Branchless online update.
        const float nm = fmaxf(mr, q);
        const float sc = EXP2F(mr - nm);
        const float t  = EXP2F(q - nm);
        lsum = fmaf(lsum, sc, t);
        acc.x = fmaf(acc.x, sc, t * xj.x);
        acc.y = fmaf(acc.y, sc, t * xj.y);
        mr = nm;
    }

    const float inv = 1.f / (lsum + EPS_C);
    const float2 b2v = *(const float2*)(bias + c2);
    float ox = fmaf(acc.x, inv, b2v.x);
    float oy = fmaf(acc.y, inv, b2v.y);
    ox = ox > 0.f ? ox : (__expf(ox) - 1.f);   // ELU
    oy = oy > 0.f ? oy : (__expf(oy) - 1.f);
    *(float2*)(out + (size_t)m * N * 128 + rowb + c2) = make_float2(ox, oy);
}

// ---------------- launch ----------------

extern "C" void kernel_launch(void* const* d_in, const int* in_sizes, int n_in,
                              void* d_out, int out_size, void* d_ws, size_t ws_size,
                              hipStream_t stream) {
    const float* x    = (const float*)d_in[0];
    const int*   ei   = (const int*)d_in[1];
    const float* ew   = (const float*)d_in[2];
    const float* Wl1  = (const float*)d_in[3];
    const float* Wr1  = (const float*)d_in[4];
    const float* att1 = (const float*)d_in[5];
    const float* We1  = (const float*)d_in[6];
    const float* b1   = (const float*)d_in[7];
    const float* Wl2  = (const float*)d_in[8];
    const float* Wr2  = (const float*)d_in[9];
    const float* att2 = (const float*)d_in[10];
    const float* We2  = (const float*)d_in[11];
    const float* b2   = (const float*)d_in[12];

    const int E = in_sizes[1] / 2;
    const int N = 5000;                 // fixed by setup_inputs
    const int R = out_size / 128;       // M*N rows
    const int M = R / N;                // B*T = 16

    char* ws = (char*)d_ws;
    size_t off = 0;
    auto alloc = [&](size_t bytes) {
        char* p = ws + off;
        off = (off + bytes + 255) & ~(size_t)255;
        return p;
    };
    int*   cnt    = (int*)  alloc((size_t)N * 4);
    float* wsum   = (float*)alloc((size_t)N * 4);
    float* selfw  = (float*)alloc((size_t)N * 4);
    int*   offs   = (int*)  alloc((size_t)(N + 1) * 4);
    int*   cursor = (int*)  alloc((size_t)N * 4);
    int2*  pairs  = (int2*) alloc((size_t)E * 8);
    float* bufA   = (float*)alloc((size_t)R * 128 * 4);
    float* bufB   = (float*)alloc((size_t)R * 128 * 4);
    float* bufC   = (float*)alloc((size_t)R * 128 * 4);

    hipMemsetAsync(cnt,    0, (size_t)N * 4, stream);
    hipMemsetAsync(wsum,   0, (size_t)N * 4, stream);
    hipMemsetAsync(cursor, 0, (size_t)N * 4, stream);

    int eb = (E + 255) / 256;
    degree_kernel<<<eb, 256, 0, stream>>>(ei, ew, E, cnt, wsum);
    scan_kernel<<<1, 1024, 0, stream>>>(cnt, wsum, N, E, offs, selfw);
    scatter_kernel<<<eb, 256, 0, stream>>>(ei, ew, E, offs, cursor, pairs);

    const int gb = R / 64;
    const int tb = (M * N + 3) / 4;

    // layer 1: K=64
    gemm2_kernel<64><<<gb, 256, 0, stream>>>(x, Wl1, Wr1, bufA, bufB, R);
    edge_kernel<<<tb, 256, 0, stream>>>(bufA, bufB, offs, pairs, selfw,
                                        att1, We1, b1, bufC, N, M);
    // layer 2: K=128
    gemm2_kernel<128><<<gb, 256, 0, stream>>>(bufC, Wl2, Wr2, bufA, bufB, R);
    edge_kernel<<<tb, 256, 0, stream>>>(bufA, bufB, offs, pairs, selfw,
                                        att2, We2, b2, (float*)d_out, N, M);
}